// Round 7
// baseline (438.238 us; speedup 1.0000x reference)
//
#include <hip/hip_runtime.h>
#include <math.h>

#define N_NODES 50000
#define N_EDGES 800000
#define N_QE    100000
#define D       128
#define NB      391        // coarse buckets of 128 nodes: (50000+127)/128
#define PCHUNK  8192       // edges per partition chunk
#define NBLKQ   3125       // agg blocks per quarter: 16 nodes/block

typedef _Float16 half4q __attribute__((ext_vector_type(4)));
typedef _Float16 half8 __attribute__((ext_vector_type(8)));
typedef short    short8 __attribute__((ext_vector_type(8)));
typedef float    f32x4 __attribute__((ext_vector_type(4)));

// fp32 -> bf16 bit pattern, round-to-nearest-even
static __device__ inline short f2bf(float f) {
    unsigned u = __builtin_bit_cast(unsigned, f);
    u += 0x7FFFu + ((u >> 16) & 1u);
    return (short)(u >> 16);
}

// ---- workspace layout (bytes) ----
static const size_t O_CNT = 0;                        // int[N]
static const size_t O_OFF = 256u * 1024;              // int[N+1]
static const size_t O_BC  = 512u * 1024;              // int[NB] bucket cursors
static const size_t O_BS  = 768u * 1024;              // int[256] block sums
static const size_t O_SRC = 1024u * 1024;             // ushort[E] (1.6 MB)
static const size_t O_TMP = 4u << 20;                 // uint[E] packed (3.2 MB)
static const size_t O_G   = 8u << 20;                 // _Float16[N*D] 12.8 MB (agg out / emb)
static const size_t O_H   = O_G + 12800000u;          // _Float16[N*D] 12.8 MB (gemm out)
static const size_t O_T   = O_H + 12800000u;          // short[5*128*128] bf16 W^T

// ---- CSR build ----
__global__ void k_count(const int* __restrict__ dst, int* __restrict__ cnt) {
    int e = blockIdx.x * 256 + threadIdx.x;
    if (e < N_EDGES) atomicAdd(&cnt[dst[e]], 1);
}

__global__ __launch_bounds__(256)
void k_scan1(const int* __restrict__ cnt, int* __restrict__ off,
             int* __restrict__ bsum) {
    __shared__ int sh[256];
    const int t = threadIdx.x;
    const int i = blockIdx.x * 256 + t;
    int v = (i < N_NODES) ? cnt[i] : 0;
    sh[t] = v;
    __syncthreads();
    #pragma unroll
    for (int o = 1; o < 256; o <<= 1) {
        int u = (t >= o) ? sh[t - o] : 0;
        __syncthreads();
        sh[t] += u;
        __syncthreads();
    }
    if (i < N_NODES) off[i] = sh[t] - v;
    if (t == 255) bsum[blockIdx.x] = sh[255];
}

__global__ __launch_bounds__(256)
void k_scan2(int* __restrict__ bsum, int nblk) {
    __shared__ int sh[256];
    const int t = threadIdx.x;
    int v = (t < nblk) ? bsum[t] : 0;
    sh[t] = v;
    __syncthreads();
    #pragma unroll
    for (int o = 1; o < 256; o <<= 1) {
        int u = (t >= o) ? sh[t - o] : 0;
        __syncthreads();
        sh[t] += u;
        __syncthreads();
    }
    if (t < nblk) bsum[t] = sh[t] - v;
}

__global__ __launch_bounds__(256)
void k_scan3(int* __restrict__ off, const int* __restrict__ bsum) {
    const int i = blockIdx.x * 256 + threadIdx.x;
    if (i < N_NODES) off[i] = off[i] + bsum[blockIdx.x];
    if (i == 0) off[N_NODES] = N_EDGES;
}

__global__ void k_binit(const int* __restrict__ off, int* __restrict__ bcur) {
    int b = blockIdx.x * 256 + threadIdx.x;
    if (b < NB) bcur[b] = off[b << 7];
}

// ---- coarse partition: edges -> 391 buckets of 128 dst-nodes ----
__global__ __launch_bounds__(256)
void k_part(const int* __restrict__ src, const int* __restrict__ dst,
            int* __restrict__ bcur, unsigned* __restrict__ tmp)
{
    __shared__ int hcnt[NB];
    __shared__ int lpos[NB];
    __shared__ int base[NB];
    const int t = threadIdx.x;
    const int e0 = blockIdx.x * PCHUNK;
    const int e1 = (e0 + PCHUNK < N_EDGES) ? e0 + PCHUNK : N_EDGES;

    for (int b = t; b < NB; b += 256) { hcnt[b] = 0; lpos[b] = 0; }
    __syncthreads();
    for (int e = e0 + t; e < e1; e += 256)
        atomicAdd(&hcnt[dst[e] >> 7], 1);
    __syncthreads();
    for (int b = t; b < NB; b += 256) {
        int c = hcnt[b];
        base[b] = c ? atomicAdd(&bcur[b], c) : 0;
    }
    __syncthreads();
    for (int e = e0 + t; e < e1; e += 256) {
        int d = dst[e];
        int b = d >> 7;
        int pos = atomicAdd(&lpos[b], 1);
        tmp[base[b] + pos] = (unsigned)src[e] | ((unsigned)(d & 127) << 16);
    }
}

// ---- fine scatter within a bucket: positions span a ~4 KB window ----
__global__ __launch_bounds__(256)
void k_fine(const unsigned* __restrict__ tmp, const int* __restrict__ off,
            unsigned short* __restrict__ srcs)
{
    __shared__ int fcur[129];
    const int t = threadIdx.x;
    const int b = blockIdx.x;
    const int n0 = b << 7;
    const int nn = (N_NODES - n0 < 128) ? N_NODES - n0 : 128;
    if (t <= nn) fcur[t] = off[n0 + t];
    const int r0 = off[n0];
    const int r1 = off[n0 + nn];
    __syncthreads();
    for (int i = r0 + t; i < r1; i += 256) {
        unsigned en = tmp[i];
        int dl = en >> 16;
        int p = atomicAdd(&fcur[dl], 1);
        srcs[p] = (unsigned short)(en & 0xFFFFu);
    }
}

// ---- weight transpose + bf16 cast: T[m][c][k] = bf16( W_m[k][c] ) ----
__global__ __launch_bounds__(256)
void k_t16all(const float* __restrict__ W1, const float* __restrict__ W2,
              const float* __restrict__ W3, const float* __restrict__ Q1,
              const float* __restrict__ Q2, short* __restrict__ T)
{
    int m = blockIdx.x >> 6;             // 0..4
    const float* S = (m == 0) ? W1 : (m == 1) ? W2 : (m == 2) ? W3
                   : (m == 3) ? Q1 : Q2;
    short* Dp = T + m * 16384;
    int idx = (blockIdx.x & 63) * 256 + threadIdx.x;   // 0..16383
    int c = idx & 127, k = idx >> 7;
    Dp[c * 128 + k] = f2bf(S[k * 128 + c]);
}

// ============================================================================
// MFMA 16x16x32_bf16 (HW-verified, learn_hip m89/m91/m97):
//   A (16x32): lane l holds A[l&15][8*(l>>4)+j], j=0..7   (short8 of bf16)
//   B (32x16): lane l holds B[8*(l>>4)+j][l&15]
//   C/D:       lane l reg i = D[(l>>4)*4 + i][l&15]
// xs[64 rows][16 slots of 8 bf16]; slot' = slot ^ (row&7) swizzle.
// ============================================================================

// ---- trunk GEMM: H16[rows x 128] = fp16( X @ W ) via bf16 MFMA ----
template<typename XT>
__global__ __launch_bounds__(256)
void k_mm(const XT* __restrict__ X, const short* __restrict__ WT,
          _Float16* __restrict__ Y, int rows)
{
    __shared__ __align__(16) short xs[64 * 128];
    const int tid = threadIdx.x;
    const int l   = tid & 63;
    const int w   = tid >> 6;
    const int g   = l >> 4;
    const int l15 = l & 15;
    const int row0 = blockIdx.x * 64;

    // stage X -> bf16 LDS (swizzled)
    {
        int r = tid >> 2;
        int gr = row0 + r; if (gr >= rows) gr = rows - 1;
        const XT* src = X + (size_t)gr * D;
        #pragma unroll
        for (int it = 0; it < 4; ++it) {
            int s = (tid & 3) + it * 4;
            short8 h;
            if constexpr (sizeof(XT) == 4) {
                float4 v0 = *(const float4*)((const float*)src + s * 8);
                float4 v1 = *(const float4*)((const float*)src + s * 8 + 4);
                h[0] = f2bf(v0.x); h[1] = f2bf(v0.y);
                h[2] = f2bf(v0.z); h[3] = f2bf(v0.w);
                h[4] = f2bf(v1.x); h[5] = f2bf(v1.y);
                h[6] = f2bf(v1.z); h[7] = f2bf(v1.w);
            } else {
                half8 v = *(const half8*)((const _Float16*)src + s * 8);
                #pragma unroll
                for (int c = 0; c < 8; ++c) h[c] = f2bf((float)v[c]);
            }
            *(short8*)&xs[r * 128 + ((s ^ (r & 7)) * 8)] = h;
        }
    }

    // W fragments for this wave's 2 col-tiles (registers)
    short8 wf[2][4];
    #pragma unroll
    for (int tt = 0; tt < 2; ++tt) {
        int c = w * 32 + tt * 16 + l15;
        #pragma unroll
        for (int s = 0; s < 4; ++s)
            wf[tt][s] = *(const short8*)(WT + (size_t)c * 128 + s * 32 + g * 8);
    }

    __syncthreads();

    f32x4 acc[4][2];
    #pragma unroll
    for (int rt = 0; rt < 4; ++rt)
        #pragma unroll
        for (int tt = 0; tt < 2; ++tt)
            acc[rt][tt] = (f32x4){0.f, 0.f, 0.f, 0.f};

    #pragma unroll
    for (int rt = 0; rt < 4; ++rt) {
        const int r = rt * 16 + l15;
        short8 a[4];
        #pragma unroll
        for (int s = 0; s < 4; ++s) {
            int slot = (4 * s + g) ^ (r & 7);
            a[s] = *(const short8*)&xs[r * 128 + slot * 8];
        }
        #pragma unroll
        for (int tt = 0; tt < 2; ++tt)
            #pragma unroll
            for (int s = 0; s < 4; ++s)
                acc[rt][tt] = __builtin_amdgcn_mfma_f32_16x16x32_bf16(
                    a[s], wf[tt][s], acc[rt][tt], 0, 0, 0);
    }

    __syncthreads();   // all A-frag reads done before overwrite

    // write C frags back to LDS as fp16 bit patterns (swizzled), then store
    #pragma unroll
    for (int rt = 0; rt < 4; ++rt)
        #pragma unroll
        for (int tt = 0; tt < 2; ++tt) {
            int c = w * 32 + tt * 16 + l15;
            #pragma unroll
            for (int i = 0; i < 4; ++i) {
                int row = rt * 16 + g * 4 + i;
                int slot = (c >> 3) ^ (row & 7);
                xs[row * 128 + slot * 8 + (c & 7)] =
                    (short)__builtin_bit_cast(unsigned short, (_Float16)acc[rt][tt][i]);
            }
        }
    __syncthreads();

    {
        int r = tid >> 2;
        int gr = row0 + r;
        if (gr < rows) {
            short* dstp = (short*)(Y + (size_t)gr * D);
            #pragma unroll
            for (int it = 0; it < 4; ++it) {
                int s = (tid & 3) + it * 4;
                *(short8*)(dstp + s * 8) =
                    *(const short8*)&xs[r * 128 + ((s ^ (r & 7)) * 8)];
            }
        }
    }
}

// ---- CSR aggregation, COLUMN-QUARTERED for per-XCD L2 residency ----
// quarter = blockIdx / NBLKQ (dispatch order separates quarters in time);
// per quarter the gather read-set is 50000*64B = 3.2 MB < 4 MiB L2/XCD.
// Wave handles 4 nodes; 8 edge slots (es) x 8B col groups (qq); fp32 acc;
// 3-level shfl_xor reduce; non-temporal 8B stores keep writes out of L2.
template<bool RELU>
__global__ __launch_bounds__(256)
void k_agg(const _Float16* __restrict__ Hin, const int* __restrict__ off,
           const unsigned short* __restrict__ srcs, const float* __restrict__ bias,
           _Float16* __restrict__ Hout)
{
    const int l   = threadIdx.x & 63;
    const int wv  = threadIdx.x >> 6;
    const int es  = l >> 3;              // 0..7 edge slot
    const int qq  = l & 7;               // col group: 4 halfs
    const int p   = blockIdx.x / NBLKQ;  // quarter 0..3
    const int nb  = blockIdx.x % NBLKQ;
    const int colbase = p * 32 + qq * 4;
    const float4 bb = *(const float4*)(bias + colbase);

    #pragma unroll
    for (int i = 0; i < 4; ++i) {
        const int n = nb * 16 + wv * 4 + i;
        const int j0 = __builtin_amdgcn_readfirstlane(off[n]);
        const int j1 = __builtin_amdgcn_readfirstlane(off[n + 1]);

        float a0 = 0.f, a1 = 0.f, a2 = 0.f, a3 = 0.f;
        for (int j = j0; j < j1; j += 8) {
            if (es < j1 - j) {
                int s = srcs[j + es];
                half4q v = *(const half4q*)(Hin + (size_t)s * D + colbase);
                a0 += (float)v[0]; a1 += (float)v[1];
                a2 += (float)v[2]; a3 += (float)v[3];
            }
        }
        #pragma unroll
        for (int m = 8; m < 64; m <<= 1) {
            a0 += __shfl_xor(a0, m, 64);
            a1 += __shfl_xor(a1, m, 64);
            a2 += __shfl_xor(a2, m, 64);
            a3 += __shfl_xor(a3, m, 64);
        }
        if (es == 0) {
            float t0 = a0 + bb.x, t1 = a1 + bb.y;
            float t2 = a2 + bb.z, t3 = a3 + bb.w;
            if (RELU) {
                t0 = fmaxf(t0, 0.f); t1 = fmaxf(t1, 0.f);
                t2 = fmaxf(t2, 0.f); t3 = fmaxf(t3, 0.f);
            }
            half4q o;
            o[0] = (_Float16)t0; o[1] = (_Float16)t1;
            o[2] = (_Float16)t2; o[3] = (_Float16)t3;
            __builtin_nontemporal_store(
                __builtin_bit_cast(unsigned long long, o),
                (unsigned long long*)(Hout + (size_t)n * D + colbase));
        }
    }
}

// ---- MFMA link predictor: 256 thr / 64 edges per block, fp16 emb gather ----
__global__ __launch_bounds__(256)
void k_predm(const _Float16* __restrict__ emb, const int* __restrict__ te,
             const short* __restrict__ P1T, const float* __restrict__ pb1,
             const short* __restrict__ P2T, const float* __restrict__ pb2,
             const float* __restrict__ P3, const float* __restrict__ pb3,
             float* __restrict__ out)
{
    __shared__ __align__(16) short xs[64 * 128];
    __shared__ float red[64][8];
    const int tid = threadIdx.x;
    const int l   = tid & 63;
    const int w   = tid >> 6;
    const int g   = l >> 4;
    const int l15 = l & 15;
    const int row0 = blockIdx.x * 64;

    // stage z0 = emb[s] * emb[d] -> bf16 LDS (swizzled)
    {
        int r = tid >> 2;
        int e = row0 + r; if (e >= N_QE) e = N_QE - 1;
        const int2 ee = *(const int2*)(te + 2 * e);
        const _Float16* sp = emb + (size_t)ee.x * D;
        const _Float16* dp = emb + (size_t)ee.y * D;
        #pragma unroll
        for (int it = 0; it < 4; ++it) {
            int s = (tid & 3) + it * 4;
            half8 a = *(const half8*)(sp + s * 8);
            half8 b = *(const half8*)(dp + s * 8);
            short8 h;
            #pragma unroll
            for (int c = 0; c < 8; ++c) h[c] = f2bf((float)a[c] * (float)b[c]);
            *(short8*)&xs[r * 128 + ((s ^ (r & 7)) * 8)] = h;
        }
    }
    __syncthreads();

    f32x4 acc[4][2];

    // ---------------- layer 1 ----------------
    {
        short8 wf[2][4];
        #pragma unroll
        for (int tt = 0; tt < 2; ++tt) {
            int c = w * 32 + tt * 16 + l15;
            #pragma unroll
            for (int s = 0; s < 4; ++s)
                wf[tt][s] = *(const short8*)(P1T + (size_t)c * 128 + s * 32 + g * 8);
        }
        #pragma unroll
        for (int rt = 0; rt < 4; ++rt)
            #pragma unroll
            for (int tt = 0; tt < 2; ++tt)
                acc[rt][tt] = (f32x4){0.f, 0.f, 0.f, 0.f};

        #pragma unroll
        for (int rt = 0; rt < 4; ++rt) {
            const int r = rt * 16 + l15;
            short8 a[4];
            #pragma unroll
            for (int s = 0; s < 4; ++s) {
                int slot = (4 * s + g) ^ (r & 7);
                a[s] = *(const short8*)&xs[r * 128 + slot * 8];
            }
            #pragma unroll
            for (int tt = 0; tt < 2; ++tt)
                #pragma unroll
                for (int s = 0; s < 4; ++s)
                    acc[rt][tt] = __builtin_amdgcn_mfma_f32_16x16x32_bf16(
                        a[s], wf[tt][s], acc[rt][tt], 0, 0, 0);
        }

        float bv[2];
        #pragma unroll
        for (int tt = 0; tt < 2; ++tt) bv[tt] = pb1[w * 32 + tt * 16 + l15];

        __syncthreads();   // reads done before overwrite

        #pragma unroll
        for (int rt = 0; rt < 4; ++rt)
            #pragma unroll
            for (int tt = 0; tt < 2; ++tt) {
                int c = w * 32 + tt * 16 + l15;
                #pragma unroll
                for (int i = 0; i < 4; ++i) {
                    float v = fmaxf(acc[rt][tt][i] + bv[tt], 0.f);
                    int row = rt * 16 + g * 4 + i;
                    int slot = (c >> 3) ^ (row & 7);
                    xs[row * 128 + slot * 8 + (c & 7)] = f2bf(v);
                }
            }
        __syncthreads();
    }

    // ---------------- layer 2 (acc kept for epilogue) ----------------
    {
        short8 wf[2][4];
        #pragma unroll
        for (int tt = 0; tt < 2; ++tt) {
            int c = w * 32 + tt * 16 + l15;
            #pragma unroll
            for (int s = 0; s < 4; ++s)
                wf[tt][s] = *(const short8*)(P2T + (size_t)c * 128 + s * 32 + g * 8);
        }
        #pragma unroll
        for (int rt = 0; rt < 4; ++rt)
            #pragma unroll
            for (int tt = 0; tt < 2; ++tt)
                acc[rt][tt] = (f32x4){0.f, 0.f, 0.f, 0.f};

        #pragma unroll
        for (int rt = 0; rt < 4; ++rt) {
            const int r = rt * 16 + l15;
            short8 a[4];
            #pragma unroll
            for (int s = 0; s < 4; ++s) {
                int slot = (4 * s + g) ^ (r & 7);
                a[s] = *(const short8*)&xs[r * 128 + slot * 8];
            }
            #pragma unroll
            for (int tt = 0; tt < 2; ++tt)
                #pragma unroll
                for (int s = 0; s < 4; ++s)
                    acc[rt][tt] = __builtin_amdgcn_mfma_f32_16x16x32_bf16(
                        a[s], wf[tt][s], acc[rt][tt], 0, 0, 0);
        }
    }

    // bias + relu on layer-2 acc, then P3 partials + reduce
    {
        float bv[2];
        float2 p3v[2];
        #pragma unroll
        for (int tt = 0; tt < 2; ++tt) {
            int c = w * 32 + tt * 16 + l15;
            bv[tt] = pb2[c];
            p3v[tt] = *(const float2*)(P3 + c * 2);
        }
        #pragma unroll
        for (int rt = 0; rt < 4; ++rt)
            #pragma unroll
            for (int i = 0; i < 4; ++i) {
                float z0 = fmaxf(acc[rt][0][i] + bv[0], 0.f);
                float z1 = fmaxf(acc[rt][1][i] + bv[1], 0.f);
                float p0 = z0 * p3v[0].x + z1 * p3v[1].x;
                float p1 = z0 * p3v[0].y + z1 * p3v[1].y;
                #pragma unroll
                for (int o = 1; o < 16; o <<= 1) {
                    p0 += __shfl_xor(p0, o, 64);
                    p1 += __shfl_xor(p1, o, 64);
                }
                if (l15 == 0) {
                    int row = rt * 16 + g * 4 + i;
                    red[row][w * 2]     = p0;
                    red[row][w * 2 + 1] = p1;
                }
            }
    }
    __syncthreads();

    if (tid < 64) {
        int gr = row0 + tid;
        if (gr < N_QE) {
            float p0 = red[tid][0] + red[tid][2] + red[tid][4] + red[tid][6] + pb3[0];
            float p1 = red[tid][1] + red[tid][3] + red[tid][5] + red[tid][7] + pb3[1];
            float nrm = fmaxf(sqrtf(p0 * p0 + p1 * p1), 1e-12f);
            p0 /= nrm; p1 /= nrm;
            float m = fmaxf(p0, p1);
            float lse = m + logf(expf(p0 - m) + expf(p1 - m));
            out[gr * 2]     = p0 - lse;
            out[gr * 2 + 1] = p1 - lse;
        }
    }
}

extern "C" void kernel_launch(void* const* d_in, const int* in_sizes, int n_in,
                              void* d_out, int out_size, void* d_ws, size_t ws_size,
                              hipStream_t stream)
{
    (void)in_sizes; (void)n_in; (void)out_size; (void)ws_size;
    const float* x   = (const float*)d_in[0];
    const int*   adj = (const int*)d_in[1];
    const int*   te  = (const int*)d_in[2];
    const float* W1  = (const float*)d_in[3];
    const float* b1  = (const float*)d_in[4];
    const float* W2  = (const float*)d_in[5];
    const float* b2  = (const float*)d_in[6];
    const float* W3  = (const float*)d_in[7];
    const float* b3  = (const float*)d_in[8];
    const float* P1  = (const float*)d_in[9];
    const float* pb1 = (const float*)d_in[10];
    const float* P2  = (const float*)d_in[11];
    const float* pb2 = (const float*)d_in[12];
    const float* P3  = (const float*)d_in[13];
    const float* pb3 = (const float*)d_in[14];
    float* out = (float*)d_out;

    char* ws = (char*)d_ws;
    int* cnt  = (int*)(ws + O_CNT);
    int* off  = (int*)(ws + O_OFF);
    int* bcur = (int*)(ws + O_BC);
    int* bsum = (int*)(ws + O_BS);
    unsigned short* srcs = (unsigned short*)(ws + O_SRC);
    unsigned* tmp = (unsigned*)(ws + O_TMP);
    _Float16* G = (_Float16*)(ws + O_G);    // fp16 agg output / emb
    _Float16* H = (_Float16*)(ws + O_H);    // fp16 gemm output (gather source)
    short*    T = (short*)(ws + O_T);       // bf16 transposed weights (5x 128x128)

    const int* esrc = adj;
    const int* edst = adj + N_EDGES;

    const int SBLK = (N_NODES + 255) / 256;   // 196

    // transposed bf16 weights (all 5 dense layers)
    k_t16all<<<320, 256, 0, stream>>>(W1, W2, W3, P1, P2, T);

    // CSR build: count -> scan -> bucket-partition -> fine scatter
    hipMemsetAsync(cnt, 0, N_NODES * sizeof(int), stream);
    k_count<<<N_EDGES / 256, 256, 0, stream>>>(edst, cnt);
    k_scan1<<<SBLK, 256, 0, stream>>>(cnt, off, bsum);
    k_scan2<<<1, 256, 0, stream>>>(bsum, SBLK);
    k_scan3<<<SBLK, 256, 0, stream>>>(off, bsum);
    k_binit<<<2, 256, 0, stream>>>(off, bcur);
    k_part<<<(N_EDGES + PCHUNK - 1) / PCHUNK, 256, 0, stream>>>(esrc, edst, bcur, tmp);
    k_fine<<<NB, 256, 0, stream>>>(tmp, off, srcs);

    const int gN = (N_NODES + 63) / 64;   // 782

    // GCN trunk: bf16-MFMA gemm (fp16 out) -> quartered agg (fp16 gather)
    k_mm<float><<<gN, 256, 0, stream>>>(x, T, H, N_NODES);
    k_agg<true><<<4 * NBLKQ, 256, 0, stream>>>(H, off, srcs, b1, G);
    k_mm<_Float16><<<gN, 256, 0, stream>>>(G, T + 16384, H, N_NODES);
    k_agg<true><<<4 * NBLKQ, 256, 0, stream>>>(H, off, srcs, b2, G);
    k_mm<_Float16><<<gN, 256, 0, stream>>>(G, T + 2 * 16384, H, N_NODES);
    k_agg<false><<<4 * NBLKQ, 256, 0, stream>>>(H, off, srcs, b3, G); // G = emb

    // bf16-MFMA link predictor (fp16 emb gather)
    const int gQ = (N_QE + 63) / 64;      // 1563
    k_predm<<<gQ, 256, 0, stream>>>(G, te, T + 3 * 16384, pb1,
                                    T + 4 * 16384, pb2, P3, pb3, out);
}

// Round 8
// 370.437 us; speedup vs baseline: 1.1830x; 1.1830x over previous
//
#include <hip/hip_runtime.h>
#include <math.h>

#define N_NODES 50000
#define N_EDGES 800000
#define N_QE    100000
#define D       128
#define NB      391        // coarse buckets of 128 nodes: (50000+127)/128
#define PCHUNK  8192       // edges per partition chunk

typedef _Float16 half8 __attribute__((ext_vector_type(8)));
typedef short    short8 __attribute__((ext_vector_type(8)));
typedef float    f32x4 __attribute__((ext_vector_type(4)));

// fp32 -> bf16 bit pattern, round-to-nearest-even
static __device__ inline short f2bf(float f) {
    unsigned u = __builtin_bit_cast(unsigned, f);
    u += 0x7FFFu + ((u >> 16) & 1u);
    return (short)(u >> 16);
}

// ---- workspace layout (bytes) ----
static const size_t O_CNT = 0;                        // int[N]
static const size_t O_OFF = 256u * 1024;              // int[N+1]
static const size_t O_BC  = 512u * 1024;              // int[NB] bucket cursors
static const size_t O_BS  = 768u * 1024;              // int[256] block sums
static const size_t O_SRC = 1024u * 1024;             // ushort[E] (1.6 MB)
static const size_t O_TMP = 4u << 20;                 // uint[E] packed (3.2 MB)
static const size_t O_G   = 8u << 20;                 // _Float16[N*D] 12.8 MB (agg out / emb)
static const size_t O_H   = O_G + 12800000u;          // _Float16[N*D] 12.8 MB (gemm out)
static const size_t O_T   = O_H + 12800000u;          // short[5*128*128] bf16 W^T

// ---- CSR build ----
__global__ void k_count(const int* __restrict__ dst, int* __restrict__ cnt) {
    int e = blockIdx.x * 256 + threadIdx.x;
    if (e < N_EDGES) atomicAdd(&cnt[dst[e]], 1);
}

__global__ __launch_bounds__(256)
void k_scan1(const int* __restrict__ cnt, int* __restrict__ off,
             int* __restrict__ bsum) {
    __shared__ int sh[256];
    const int t = threadIdx.x;
    const int i = blockIdx.x * 256 + t;
    int v = (i < N_NODES) ? cnt[i] : 0;
    sh[t] = v;
    __syncthreads();
    #pragma unroll
    for (int o = 1; o < 256; o <<= 1) {
        int u = (t >= o) ? sh[t - o] : 0;
        __syncthreads();
        sh[t] += u;
        __syncthreads();
    }
    if (i < N_NODES) off[i] = sh[t] - v;
    if (t == 255) bsum[blockIdx.x] = sh[255];
}

__global__ __launch_bounds__(256)
void k_scan2(int* __restrict__ bsum, int nblk) {
    __shared__ int sh[256];
    const int t = threadIdx.x;
    int v = (t < nblk) ? bsum[t] : 0;
    sh[t] = v;
    __syncthreads();
    #pragma unroll
    for (int o = 1; o < 256; o <<= 1) {
        int u = (t >= o) ? sh[t - o] : 0;
        __syncthreads();
        sh[t] += u;
        __syncthreads();
    }
    if (t < nblk) bsum[t] = sh[t] - v;
}

__global__ __launch_bounds__(256)
void k_scan3(int* __restrict__ off, const int* __restrict__ bsum) {
    const int i = blockIdx.x * 256 + threadIdx.x;
    if (i < N_NODES) off[i] = off[i] + bsum[blockIdx.x];
    if (i == 0) off[N_NODES] = N_EDGES;
}

__global__ void k_binit(const int* __restrict__ off, int* __restrict__ bcur) {
    int b = blockIdx.x * 256 + threadIdx.x;
    if (b < NB) bcur[b] = off[b << 7];
}

// ---- coarse partition: edges -> 391 buckets of 128 dst-nodes ----
__global__ __launch_bounds__(256)
void k_part(const int* __restrict__ src, const int* __restrict__ dst,
            int* __restrict__ bcur, unsigned* __restrict__ tmp)
{
    __shared__ int hcnt[NB];
    __shared__ int lpos[NB];
    __shared__ int base[NB];
    const int t = threadIdx.x;
    const int e0 = blockIdx.x * PCHUNK;
    const int e1 = (e0 + PCHUNK < N_EDGES) ? e0 + PCHUNK : N_EDGES;

    for (int b = t; b < NB; b += 256) { hcnt[b] = 0; lpos[b] = 0; }
    __syncthreads();
    for (int e = e0 + t; e < e1; e += 256)
        atomicAdd(&hcnt[dst[e] >> 7], 1);
    __syncthreads();
    for (int b = t; b < NB; b += 256) {
        int c = hcnt[b];
        base[b] = c ? atomicAdd(&bcur[b], c) : 0;
    }
    __syncthreads();
    for (int e = e0 + t; e < e1; e += 256) {
        int d = dst[e];
        int b = d >> 7;
        int pos = atomicAdd(&lpos[b], 1);
        tmp[base[b] + pos] = (unsigned)src[e] | ((unsigned)(d & 127) << 16);
    }
}

// ---- fine scatter + per-node ASCENDING sort (LDS-staged) ----
// Sorted src lists => concurrent waves (walking equal-rank slots of uniform
// random lists) gather from a narrow ascending band of H -> L2-resident.
__global__ __launch_bounds__(256)
void k_fine(const unsigned* __restrict__ tmp, const int* __restrict__ off,
            unsigned short* __restrict__ srcs)
{
    __shared__ unsigned short buf[4096];
    __shared__ int fcur[129];
    __shared__ int foff[129];
    const int t = threadIdx.x;
    const int b = blockIdx.x;
    const int n0 = b << 7;
    const int nn = (N_NODES - n0 < 128) ? N_NODES - n0 : 128;
    const int r0 = off[n0];
    const int r1 = off[n0 + nn];
    if (t <= nn) {
        int o = off[n0 + t] - r0;
        fcur[t] = o; foff[t] = o;
    }
    __syncthreads();
    const int sz = r1 - r0;

    if (sz <= 4096) {
        for (int i = r0 + t; i < r1; i += 256) {
            unsigned en = tmp[i];
            int p = atomicAdd(&fcur[en >> 16], 1);
            buf[p] = (unsigned short)(en & 0xFFFFu);
        }
        __syncthreads();
        if (t < nn) {                       // insertion-sort node t's segment
            int s0 = foff[t], s1 = foff[t + 1];
            for (int i = s0 + 1; i < s1; ++i) {
                unsigned short key = buf[i];
                int k = i - 1;
                while (k >= s0 && buf[k] > key) { buf[k + 1] = buf[k]; --k; }
                buf[k + 1] = key;
            }
        }
        __syncthreads();
        for (int i = t; i < sz; i += 256) srcs[r0 + i] = buf[i];
    } else {                                // overflow fallback (unsorted)
        for (int i = r0 + t; i < r1; i += 256) {
            unsigned en = tmp[i];
            int p = atomicAdd(&fcur[en >> 16], 1);
            srcs[r0 + p] = (unsigned short)(en & 0xFFFFu);
        }
    }
}

// ---- weight transpose + bf16 cast: T[m][c][k] = bf16( W_m[k][c] ) ----
__global__ __launch_bounds__(256)
void k_t16all(const float* __restrict__ W1, const float* __restrict__ W2,
              const float* __restrict__ W3, const float* __restrict__ Q1,
              const float* __restrict__ Q2, short* __restrict__ T)
{
    int m = blockIdx.x >> 6;             // 0..4
    const float* S = (m == 0) ? W1 : (m == 1) ? W2 : (m == 2) ? W3
                   : (m == 3) ? Q1 : Q2;
    short* Dp = T + m * 16384;
    int idx = (blockIdx.x & 63) * 256 + threadIdx.x;   // 0..16383
    int c = idx & 127, k = idx >> 7;
    Dp[c * 128 + k] = f2bf(S[k * 128 + c]);
}

// ============================================================================
// MFMA 16x16x32_bf16 (HW-verified, learn_hip m89/m91/m97):
//   A (16x32): lane l holds A[l&15][8*(l>>4)+j], j=0..7   (short8 of bf16)
//   B (32x16): lane l holds B[8*(l>>4)+j][l&15]
//   C/D:       lane l reg i = D[(l>>4)*4 + i][l&15]
// xs[64 rows][16 slots of 8 bf16]; slot' = slot ^ (row&7) swizzle.
// ============================================================================

// ---- trunk GEMM: H16[rows x 128] = fp16( X @ W ) via bf16 MFMA ----
template<typename XT>
__global__ __launch_bounds__(256)
void k_mm(const XT* __restrict__ X, const short* __restrict__ WT,
          _Float16* __restrict__ Y, int rows)
{
    __shared__ __align__(16) short xs[64 * 128];
    const int tid = threadIdx.x;
    const int l   = tid & 63;
    const int w   = tid >> 6;
    const int g   = l >> 4;
    const int l15 = l & 15;
    const int row0 = blockIdx.x * 64;

    // stage X -> bf16 LDS (swizzled)
    {
        int r = tid >> 2;
        int gr = row0 + r; if (gr >= rows) gr = rows - 1;
        const XT* src = X + (size_t)gr * D;
        #pragma unroll
        for (int it = 0; it < 4; ++it) {
            int s = (tid & 3) + it * 4;
            short8 h;
            if constexpr (sizeof(XT) == 4) {
                float4 v0 = *(const float4*)((const float*)src + s * 8);
                float4 v1 = *(const float4*)((const float*)src + s * 8 + 4);
                h[0] = f2bf(v0.x); h[1] = f2bf(v0.y);
                h[2] = f2bf(v0.z); h[3] = f2bf(v0.w);
                h[4] = f2bf(v1.x); h[5] = f2bf(v1.y);
                h[6] = f2bf(v1.z); h[7] = f2bf(v1.w);
            } else {
                half8 v = *(const half8*)((const _Float16*)src + s * 8);
                #pragma unroll
                for (int c = 0; c < 8; ++c) h[c] = f2bf((float)v[c]);
            }
            *(short8*)&xs[r * 128 + ((s ^ (r & 7)) * 8)] = h;
        }
    }

    // W fragments for this wave's 2 col-tiles (registers)
    short8 wf[2][4];
    #pragma unroll
    for (int tt = 0; tt < 2; ++tt) {
        int c = w * 32 + tt * 16 + l15;
        #pragma unroll
        for (int s = 0; s < 4; ++s)
            wf[tt][s] = *(const short8*)(WT + (size_t)c * 128 + s * 32 + g * 8);
    }

    __syncthreads();

    f32x4 acc[4][2];
    #pragma unroll
    for (int rt = 0; rt < 4; ++rt)
        #pragma unroll
        for (int tt = 0; tt < 2; ++tt)
            acc[rt][tt] = (f32x4){0.f, 0.f, 0.f, 0.f};

    #pragma unroll
    for (int rt = 0; rt < 4; ++rt) {
        const int r = rt * 16 + l15;
        short8 a[4];
        #pragma unroll
        for (int s = 0; s < 4; ++s) {
            int slot = (4 * s + g) ^ (r & 7);
            a[s] = *(const short8*)&xs[r * 128 + slot * 8];
        }
        #pragma unroll
        for (int tt = 0; tt < 2; ++tt)
            #pragma unroll
            for (int s = 0; s < 4; ++s)
                acc[rt][tt] = __builtin_amdgcn_mfma_f32_16x16x32_bf16(
                    a[s], wf[tt][s], acc[rt][tt], 0, 0, 0);
    }

    __syncthreads();   // all A-frag reads done before overwrite

    // write C frags back to LDS as fp16 bit patterns (swizzled), then store
    #pragma unroll
    for (int rt = 0; rt < 4; ++rt)
        #pragma unroll
        for (int tt = 0; tt < 2; ++tt) {
            int c = w * 32 + tt * 16 + l15;
            #pragma unroll
            for (int i = 0; i < 4; ++i) {
                int row = rt * 16 + g * 4 + i;
                int slot = (c >> 3) ^ (row & 7);
                xs[row * 128 + slot * 8 + (c & 7)] =
                    (short)__builtin_bit_cast(unsigned short, (_Float16)acc[rt][tt][i]);
            }
        }
    __syncthreads();

    {
        int r = tid >> 2;
        int gr = row0 + r;
        if (gr < rows) {
            short* dstp = (short*)(Y + (size_t)gr * D);
            #pragma unroll
            for (int it = 0; it < 4; ++it) {
                int s = (tid & 3) + it * 4;
                *(short8*)(dstp + s * 8) =
                    *(const short8*)&xs[r * 128 + ((s ^ (r & 7)) * 8)];
            }
        }
    }
}

// ---- CSR aggregation (R6 version): fp16 gather (16B/lane, 4 edges/wave
// instr), fp32 accumulate, fp16 out. One node per wave; es=l>>4 edge slot,
// q=l&15 col group. Cross-slot combine via shfl_xor(16,32). srcs SORTED
// ascending per node (k_fine) for machine-wide gather locality.
template<bool RELU>
__global__ __launch_bounds__(256)
void k_agg(const _Float16* __restrict__ Hin, const int* __restrict__ off,
           const unsigned short* __restrict__ srcs, const float* __restrict__ bias,
           _Float16* __restrict__ Hout)
{
    const int lane = threadIdx.x & 63;
    const int es   = lane >> 4;          // 0..3  edge slot
    const int q    = lane & 15;          // col group 8q..8q+7
    const int wv   = threadIdx.x >> 6;
    const int n    = blockIdx.x * 4 + wv;
    const int j0 = __builtin_amdgcn_readfirstlane(off[n]);
    const int j1 = __builtin_amdgcn_readfirstlane(off[n + 1]);

    float acc[8] = {};
    int j = j0;

    for (; j + 16 <= j1; j += 16) {
        half8 v[4];
        #pragma unroll
        for (int k = 0; k < 4; ++k) {
            int s = srcs[j + 4 * k + es];
            v[k] = *(const half8*)(Hin + (size_t)s * D + q * 8);
        }
        #pragma unroll
        for (int k = 0; k < 4; ++k)
            #pragma unroll
            for (int c = 0; c < 8; ++c) acc[c] += (float)v[k][c];
    }
    for (; j + 4 <= j1; j += 4) {
        int s = srcs[j + es];
        half8 v = *(const half8*)(Hin + (size_t)s * D + q * 8);
        #pragma unroll
        for (int c = 0; c < 8; ++c) acc[c] += (float)v[c];
    }
    {
        int rem = j1 - j;            // 0..3
        if (rem > 0) {
            int s = srcs[j + (es < rem ? es : rem - 1)];
            half8 v = *(const half8*)(Hin + (size_t)s * D + q * 8);
            if (es < rem) {
                #pragma unroll
                for (int c = 0; c < 8; ++c) acc[c] += (float)v[c];
            }
        }
    }

    #pragma unroll
    for (int c = 0; c < 8; ++c) {
        acc[c] += __shfl_xor(acc[c], 16, 64);
        acc[c] += __shfl_xor(acc[c], 32, 64);
    }

    if (es == 0) {
        half8 o;
        #pragma unroll
        for (int c = 0; c < 8; ++c) {
            float t = acc[c] + bias[q * 8 + c];
            if (RELU) t = fmaxf(t, 0.f);
            o[c] = (_Float16)t;
        }
        *(half8*)(Hout + (size_t)n * D + q * 8) = o;
    }
}

// ---- MFMA link predictor: 256 thr / 64 edges per block, fp16 emb gather ----
__global__ __launch_bounds__(256)
void k_predm(const _Float16* __restrict__ emb, const int* __restrict__ te,
             const short* __restrict__ P1T, const float* __restrict__ pb1,
             const short* __restrict__ P2T, const float* __restrict__ pb2,
             const float* __restrict__ P3, const float* __restrict__ pb3,
             float* __restrict__ out)
{
    __shared__ __align__(16) short xs[64 * 128];
    __shared__ float red[64][8];
    const int tid = threadIdx.x;
    const int l   = tid & 63;
    const int w   = tid >> 6;
    const int g   = l >> 4;
    const int l15 = l & 15;
    const int row0 = blockIdx.x * 64;

    // stage z0 = emb[s] * emb[d] -> bf16 LDS (swizzled)
    {
        int r = tid >> 2;
        int e = row0 + r; if (e >= N_QE) e = N_QE - 1;
        const int2 ee = *(const int2*)(te + 2 * e);
        const _Float16* sp = emb + (size_t)ee.x * D;
        const _Float16* dp = emb + (size_t)ee.y * D;
        #pragma unroll
        for (int it = 0; it < 4; ++it) {
            int s = (tid & 3) + it * 4;
            half8 a = *(const half8*)(sp + s * 8);
            half8 b = *(const half8*)(dp + s * 8);
            short8 h;
            #pragma unroll
            for (int c = 0; c < 8; ++c) h[c] = f2bf((float)a[c] * (float)b[c]);
            *(short8*)&xs[r * 128 + ((s ^ (r & 7)) * 8)] = h;
        }
    }
    __syncthreads();

    f32x4 acc[4][2];

    // ---------------- layer 1 ----------------
    {
        short8 wf[2][4];
        #pragma unroll
        for (int tt = 0; tt < 2; ++tt) {
            int c = w * 32 + tt * 16 + l15;
            #pragma unroll
            for (int s = 0; s < 4; ++s)
                wf[tt][s] = *(const short8*)(P1T + (size_t)c * 128 + s * 32 + g * 8);
        }
        #pragma unroll
        for (int rt = 0; rt < 4; ++rt)
            #pragma unroll
            for (int tt = 0; tt < 2; ++tt)
                acc[rt][tt] = (f32x4){0.f, 0.f, 0.f, 0.f};

        #pragma unroll
        for (int rt = 0; rt < 4; ++rt) {
            const int r = rt * 16 + l15;
            short8 a[4];
            #pragma unroll
            for (int s = 0; s < 4; ++s) {
                int slot = (4 * s + g) ^ (r & 7);
                a[s] = *(const short8*)&xs[r * 128 + slot * 8];
            }
            #pragma unroll
            for (int tt = 0; tt < 2; ++tt)
                #pragma unroll
                for (int s = 0; s < 4; ++s)
                    acc[rt][tt] = __builtin_amdgcn_mfma_f32_16x16x32_bf16(
                        a[s], wf[tt][s], acc[rt][tt], 0, 0, 0);
        }

        float bv[2];
        #pragma unroll
        for (int tt = 0; tt < 2; ++tt) bv[tt] = pb1[w * 32 + tt * 16 + l15];

        __syncthreads();   // reads done before overwrite

        #pragma unroll
        for (int rt = 0; rt < 4; ++rt)
            #pragma unroll
            for (int tt = 0; tt < 2; ++tt) {
                int c = w * 32 + tt * 16 + l15;
                #pragma unroll
                for (int i = 0; i < 4; ++i) {
                    float v = fmaxf(acc[rt][tt][i] + bv[tt], 0.f);
                    int row = rt * 16 + g * 4 + i;
                    int slot = (c >> 3) ^ (row & 7);
                    xs[row * 128 + slot * 8 + (c & 7)] = f2bf(v);
                }
            }
        __syncthreads();
    }

    // ---------------- layer 2 (acc kept for epilogue) ----------------
    {
        short8 wf[2][4];
        #pragma unroll
        for (int tt = 0; tt < 2; ++tt) {
            int c = w * 32 + tt * 16 + l15;
            #pragma unroll
            for (int s = 0; s < 4; ++s)
                wf[tt][s] = *(const short8*)(P2T + (size_t)c * 128 + s * 32 + g * 8);
        }
        #pragma unroll
        for (int rt = 0; rt < 4; ++rt)
            #pragma unroll
            for (int tt = 0; tt < 2; ++tt)
                acc[rt][tt] = (f32x4){0.f, 0.f, 0.f, 0.f};

        #pragma unroll
        for (int rt = 0; rt < 4; ++rt) {
            const int r = rt * 16 + l15;
            short8 a[4];
            #pragma unroll
            for (int s = 0; s < 4; ++s) {
                int slot = (4 * s + g) ^ (r & 7);
                a[s] = *(const short8*)&xs[r * 128 + slot * 8];
            }
            #pragma unroll
            for (int tt = 0; tt < 2; ++tt)
                #pragma unroll
                for (int s = 0; s < 4; ++s)
                    acc[rt][tt] = __builtin_amdgcn_mfma_f32_16x16x32_bf16(
                        a[s], wf[tt][s], acc[rt][tt], 0, 0, 0);
        }
    }

    // bias + relu on layer-2 acc, then P3 partials + reduce
    {
        float bv[2];
        float2 p3v[2];
        #pragma unroll
        for (int tt = 0; tt < 2; ++tt) {
            int c = w * 32 + tt * 16 + l15;
            bv[tt] = pb2[c];
            p3v[tt] = *(const float2*)(P3 + c * 2);
        }
        #pragma unroll
        for (int rt = 0; rt < 4; ++rt)
            #pragma unroll
            for (int i = 0; i < 4; ++i) {
                float z0 = fmaxf(acc[rt][0][i] + bv[0], 0.f);
                float z1 = fmaxf(acc[rt][1][i] + bv[1], 0.f);
                float p0 = z0 * p3v[0].x + z1 * p3v[1].x;
                float p1 = z0 * p3v[0].y + z1 * p3v[1].y;
                #pragma unroll
                for (int o = 1; o < 16; o <<= 1) {
                    p0 += __shfl_xor(p0, o, 64);
                    p1 += __shfl_xor(p1, o, 64);
                }
                if (l15 == 0) {
                    int row = rt * 16 + g * 4 + i;
                    red[row][w * 2]     = p0;
                    red[row][w * 2 + 1] = p1;
                }
            }
    }
    __syncthreads();

    if (tid < 64) {
        int gr = row0 + tid;
        if (gr < N_QE) {
            float p0 = red[tid][0] + red[tid][2] + red[tid][4] + red[tid][6] + pb3[0];
            float p1 = red[tid][1] + red[tid][3] + red[tid][5] + red[tid][7] + pb3[1];
            float nrm = fmaxf(sqrtf(p0 * p0 + p1 * p1), 1e-12f);
            p0 /= nrm; p1 /= nrm;
            float m = fmaxf(p0, p1);
            float lse = m + logf(expf(p0 - m) + expf(p1 - m));
            out[gr * 2]     = p0 - lse;
            out[gr * 2 + 1] = p1 - lse;
        }
    }
}

extern "C" void kernel_launch(void* const* d_in, const int* in_sizes, int n_in,
                              void* d_out, int out_size, void* d_ws, size_t ws_size,
                              hipStream_t stream)
{
    (void)in_sizes; (void)n_in; (void)out_size; (void)ws_size;
    const float* x   = (const float*)d_in[0];
    const int*   adj = (const int*)d_in[1];
    const int*   te  = (const int*)d_in[2];
    const float* W1  = (const float*)d_in[3];
    const float* b1  = (const float*)d_in[4];
    const float* W2  = (const float*)d_in[5];
    const float* b2  = (const float*)d_in[6];
    const float* W3  = (const float*)d_in[7];
    const float* b3  = (const float*)d_in[8];
    const float* P1  = (const float*)d_in[9];
    const float* pb1 = (const float*)d_in[10];
    const float* P2  = (const float*)d_in[11];
    const float* pb2 = (const float*)d_in[12];
    const float* P3  = (const float*)d_in[13];
    const float* pb3 = (const float*)d_in[14];
    float* out = (float*)d_out;

    char* ws = (char*)d_ws;
    int* cnt  = (int*)(ws + O_CNT);
    int* off  = (int*)(ws + O_OFF);
    int* bcur = (int*)(ws + O_BC);
    int* bsum = (int*)(ws + O_BS);
    unsigned short* srcs = (unsigned short*)(ws + O_SRC);
    unsigned* tmp = (unsigned*)(ws + O_TMP);
    _Float16* G = (_Float16*)(ws + O_G);    // fp16 agg output / emb
    _Float16* H = (_Float16*)(ws + O_H);    // fp16 gemm output (gather source)
    short*    T = (short*)(ws + O_T);       // bf16 transposed weights (5x 128x128)

    const int* esrc = adj;
    const int* edst = adj + N_EDGES;

    const int SBLK = (N_NODES + 255) / 256;   // 196

    // transposed bf16 weights (all 5 dense layers)
    k_t16all<<<320, 256, 0, stream>>>(W1, W2, W3, P1, P2, T);

    // CSR build: count -> scan -> bucket-partition -> fine scatter + sort
    hipMemsetAsync(cnt, 0, N_NODES * sizeof(int), stream);
    k_count<<<N_EDGES / 256, 256, 0, stream>>>(edst, cnt);
    k_scan1<<<SBLK, 256, 0, stream>>>(cnt, off, bsum);
    k_scan2<<<1, 256, 0, stream>>>(bsum, SBLK);
    k_scan3<<<SBLK, 256, 0, stream>>>(off, bsum);
    k_binit<<<2, 256, 0, stream>>>(off, bcur);
    k_part<<<(N_EDGES + PCHUNK - 1) / PCHUNK, 256, 0, stream>>>(esrc, edst, bcur, tmp);
    k_fine<<<NB, 256, 0, stream>>>(tmp, off, srcs);

    const int gN = (N_NODES + 63) / 64;   // 782

    // GCN trunk: bf16-MFMA gemm (fp16 out) -> agg (fp16 gather, fp16 out)
    k_mm<float><<<gN, 256, 0, stream>>>(x, T, H, N_NODES);
    k_agg<true><<<N_NODES / 4, 256, 0, stream>>>(H, off, srcs, b1, G);
    k_mm<_Float16><<<gN, 256, 0, stream>>>(G, T + 16384, H, N_NODES);
    k_agg<true><<<N_NODES / 4, 256, 0, stream>>>(H, off, srcs, b2, G);
    k_mm<_Float16><<<gN, 256, 0, stream>>>(G, T + 2 * 16384, H, N_NODES);
    k_agg<false><<<N_NODES / 4, 256, 0, stream>>>(H, off, srcs, b3, G); // G = emb

    // bf16-MFMA link predictor (fp16 emb gather)
    const int gQ = (N_QE + 63) / 64;      // 1563
    k_predm<<<gQ, 256, 0, stream>>>(G, te, T + 3 * 16384, pb1,
                                    T + 4 * 16384, pb2, P3, pb3, out);
}

// Round 9
// 298.059 us; speedup vs baseline: 1.4703x; 1.2428x over previous
//
#include <hip/hip_runtime.h>
#include <math.h>

#define N_NODES 50000
#define N_EDGES 800000
#define N_QE    100000
#define D       128
#define NB      391        // coarse buckets of 128 nodes: (50000+127)/128
#define PCHUNK  8192       // edges per partition chunk

typedef _Float16 half8 __attribute__((ext_vector_type(8)));
typedef short    short8 __attribute__((ext_vector_type(8)));
typedef float    f32x4 __attribute__((ext_vector_type(4)));

// fp32 -> bf16 bit pattern, round-to-nearest-even
static __device__ inline short f2bf(float f) {
    unsigned u = __builtin_bit_cast(unsigned, f);
    u += 0x7FFFu + ((u >> 16) & 1u);
    return (short)(u >> 16);
}

// ---- workspace layout (bytes) ----
static const size_t O_BCNT = 0;                       // int[NB] bucket counts
static const size_t O_OFF  = 256u * 1024;             // int[N+1]
static const size_t O_BC   = 512u * 1024;             // int[NB] bucket cursors (k_part)
static const size_t O_BB   = 768u * 1024;             // int[NB+1] bucket bases
static const size_t O_SRC  = 1024u * 1024;            // ushort[E] (1.6 MB)
static const size_t O_TMP  = 4u << 20;                // uint[E] packed (3.2 MB)
static const size_t O_G    = 8u << 20;                // _Float16[N*D] 12.8 MB (agg out / emb)
static const size_t O_H    = O_G + 12800000u;         // _Float16[N*D] 12.8 MB (gemm out)
static const size_t O_T    = O_H + 12800000u;         // short[5*128*128] bf16 W^T

// ---- CSR build (bucket-level only; per-node offsets come from k_fine2) ----

// bucket histogram per chunk (LDS) -> 391 global atomics per chunk
__global__ __launch_bounds__(256)
void k_bcount(const int* __restrict__ dst, int* __restrict__ bcnt) {
    __shared__ int h[NB];
    const int t = threadIdx.x;
    const int e0 = blockIdx.x * PCHUNK;
    const int e1 = (e0 + PCHUNK < N_EDGES) ? e0 + PCHUNK : N_EDGES;
    for (int b = t; b < NB; b += 256) h[b] = 0;
    __syncthreads();
    for (int e = e0 + t; e < e1; e += 256)
        atomicAdd(&h[dst[e] >> 7], 1);
    __syncthreads();
    for (int b = t; b < NB; b += 256)
        if (h[b]) atomicAdd(&bcnt[b], h[b]);
}

// single-block exclusive scan over NB buckets -> bbase (and bcur copy)
__global__ __launch_bounds__(512)
void k_bscan(const int* __restrict__ bcnt, int* __restrict__ bbase,
             int* __restrict__ bcur, int* __restrict__ off) {
    __shared__ int sh[512];
    const int t = threadIdx.x;
    int v = (t < NB) ? bcnt[t] : 0;
    sh[t] = v;
    __syncthreads();
    #pragma unroll
    for (int o = 1; o < 512; o <<= 1) {
        int u = (t >= o) ? sh[t - o] : 0;
        __syncthreads();
        sh[t] += u;
        __syncthreads();
    }
    if (t < NB) { int e = sh[t] - v; bbase[t] = e; bcur[t] = e; }
    if (t == 0) { bbase[NB] = N_EDGES; off[N_NODES] = N_EDGES; }
}

// ---- coarse partition: edges -> 391 buckets of 128 dst-nodes ----
__global__ __launch_bounds__(256)
void k_part(const int* __restrict__ src, const int* __restrict__ dst,
            int* __restrict__ bcur, unsigned* __restrict__ tmp)
{
    __shared__ int hcnt[NB];
    __shared__ int lpos[NB];
    __shared__ int base[NB];
    const int t = threadIdx.x;
    const int e0 = blockIdx.x * PCHUNK;
    const int e1 = (e0 + PCHUNK < N_EDGES) ? e0 + PCHUNK : N_EDGES;

    for (int b = t; b < NB; b += 256) { hcnt[b] = 0; lpos[b] = 0; }
    __syncthreads();
    for (int e = e0 + t; e < e1; e += 256)
        atomicAdd(&hcnt[dst[e] >> 7], 1);
    __syncthreads();
    for (int b = t; b < NB; b += 256) {
        int c = hcnt[b];
        base[b] = c ? atomicAdd(&bcur[b], c) : 0;
    }
    __syncthreads();
    for (int e = e0 + t; e < e1; e += 256) {
        int d = dst[e];
        int b = d >> 7;
        int pos = atomicAdd(&lpos[b], 1);
        tmp[base[b] + pos] = (unsigned)src[e] | ((unsigned)(d & 127) << 16);
    }
}

// ---- fine: per-node LDS count + scan -> off[], then in-bucket scatter ----
__global__ __launch_bounds__(256)
void k_fine2(const unsigned* __restrict__ tmp, const int* __restrict__ bbase,
             unsigned short* __restrict__ srcs, int* __restrict__ off)
{
    __shared__ int ncnt[128];
    __shared__ int fcur[128];
    const int t = threadIdx.x;
    const int b = blockIdx.x;
    const int n0 = b << 7;
    const int nn = (N_NODES - n0 < 128) ? N_NODES - n0 : 128;
    const int r0 = bbase[b];
    const int r1 = bbase[b + 1];

    if (t < 128) ncnt[t] = 0;
    __syncthreads();
    for (int i = r0 + t; i < r1; i += 256)
        atomicAdd(&ncnt[tmp[i] >> 16], 1);
    __syncthreads();
    int c = (t < 128) ? ncnt[t] : 0;            // own count
    #pragma unroll
    for (int o = 1; o < 128; o <<= 1) {
        int u = (t >= o && t < 128) ? ncnt[t - o] : 0;
        __syncthreads();
        if (t < 128) ncnt[t] += u;
        __syncthreads();
    }
    if (t < 128) {
        int excl = r0 + ncnt[t] - c;            // exclusive prefix
        fcur[t] = excl;
        if (t < nn) off[n0 + t] = excl;
    }
    __syncthreads();
    for (int i = r0 + t; i < r1; i += 256) {
        unsigned en = tmp[i];
        int p = atomicAdd(&fcur[en >> 16], 1);
        srcs[p] = (unsigned short)(en & 0xFFFFu);
    }
}

// ---- weight transpose + bf16 cast: T[m][c][k] = bf16( W_m[k][c] ) ----
__global__ __launch_bounds__(256)
void k_t16all(const float* __restrict__ W1, const float* __restrict__ W2,
              const float* __restrict__ W3, const float* __restrict__ Q1,
              const float* __restrict__ Q2, short* __restrict__ T)
{
    int m = blockIdx.x >> 6;             // 0..4
    const float* S = (m == 0) ? W1 : (m == 1) ? W2 : (m == 2) ? W3
                   : (m == 3) ? Q1 : Q2;
    short* Dp = T + m * 16384;
    int idx = (blockIdx.x & 63) * 256 + threadIdx.x;   // 0..16383
    int c = idx & 127, k = idx >> 7;
    Dp[c * 128 + k] = f2bf(S[k * 128 + c]);
}

// ============================================================================
// MFMA 16x16x32_bf16 (HW-verified, learn_hip m89/m91/m97):
//   A (16x32): lane l holds A[l&15][8*(l>>4)+j], j=0..7   (short8 of bf16)
//   B (32x16): lane l holds B[8*(l>>4)+j][l&15]
//   C/D:       lane l reg i = D[(l>>4)*4 + i][l&15]
// xs[64 rows][16 slots of 8 bf16]; slot' = slot ^ (row&7) swizzle.
// ============================================================================

// ---- trunk GEMM: H16[rows x 128] = fp16( X @ W ) via bf16 MFMA ----
template<typename XT>
__global__ __launch_bounds__(256)
void k_mm(const XT* __restrict__ X, const short* __restrict__ WT,
          _Float16* __restrict__ Y, int rows)
{
    __shared__ __align__(16) short xs[64 * 128];
    const int tid = threadIdx.x;
    const int l   = tid & 63;
    const int w   = tid >> 6;
    const int g   = l >> 4;
    const int l15 = l & 15;
    const int row0 = blockIdx.x * 64;

    // stage X -> bf16 LDS (swizzled)
    {
        int r = tid >> 2;
        int gr = row0 + r; if (gr >= rows) gr = rows - 1;
        const XT* src = X + (size_t)gr * D;
        #pragma unroll
        for (int it = 0; it < 4; ++it) {
            int s = (tid & 3) + it * 4;
            short8 h;
            if constexpr (sizeof(XT) == 4) {
                float4 v0 = *(const float4*)((const float*)src + s * 8);
                float4 v1 = *(const float4*)((const float*)src + s * 8 + 4);
                h[0] = f2bf(v0.x); h[1] = f2bf(v0.y);
                h[2] = f2bf(v0.z); h[3] = f2bf(v0.w);
                h[4] = f2bf(v1.x); h[5] = f2bf(v1.y);
                h[6] = f2bf(v1.z); h[7] = f2bf(v1.w);
            } else {
                half8 v = *(const half8*)((const _Float16*)src + s * 8);
                #pragma unroll
                for (int c = 0; c < 8; ++c) h[c] = f2bf((float)v[c]);
            }
            *(short8*)&xs[r * 128 + ((s ^ (r & 7)) * 8)] = h;
        }
    }

    // W fragments for this wave's 2 col-tiles (registers)
    short8 wf[2][4];
    #pragma unroll
    for (int tt = 0; tt < 2; ++tt) {
        int c = w * 32 + tt * 16 + l15;
        #pragma unroll
        for (int s = 0; s < 4; ++s)
            wf[tt][s] = *(const short8*)(WT + (size_t)c * 128 + s * 32 + g * 8);
    }

    __syncthreads();

    f32x4 acc[4][2];
    #pragma unroll
    for (int rt = 0; rt < 4; ++rt)
        #pragma unroll
        for (int tt = 0; tt < 2; ++tt)
            acc[rt][tt] = (f32x4){0.f, 0.f, 0.f, 0.f};

    #pragma unroll
    for (int rt = 0; rt < 4; ++rt) {
        const int r = rt * 16 + l15;
        short8 a[4];
        #pragma unroll
        for (int s = 0; s < 4; ++s) {
            int slot = (4 * s + g) ^ (r & 7);
            a[s] = *(const short8*)&xs[r * 128 + slot * 8];
        }
        #pragma unroll
        for (int tt = 0; tt < 2; ++tt)
            #pragma unroll
            for (int s = 0; s < 4; ++s)
                acc[rt][tt] = __builtin_amdgcn_mfma_f32_16x16x32_bf16(
                    a[s], wf[tt][s], acc[rt][tt], 0, 0, 0);
    }

    __syncthreads();   // all A-frag reads done before overwrite

    // write C frags back to LDS as fp16 bit patterns (swizzled), then store
    #pragma unroll
    for (int rt = 0; rt < 4; ++rt)
        #pragma unroll
        for (int tt = 0; tt < 2; ++tt) {
            int c = w * 32 + tt * 16 + l15;
            #pragma unroll
            for (int i = 0; i < 4; ++i) {
                int row = rt * 16 + g * 4 + i;
                int slot = (c >> 3) ^ (row & 7);
                xs[row * 128 + slot * 8 + (c & 7)] =
                    (short)__builtin_bit_cast(unsigned short, (_Float16)acc[rt][tt][i]);
            }
        }
    __syncthreads();

    {
        int r = tid >> 2;
        int gr = row0 + r;
        if (gr < rows) {
            short* dstp = (short*)(Y + (size_t)gr * D);
            #pragma unroll
            for (int it = 0; it < 4; ++it) {
                int s = (tid & 3) + it * 4;
                *(short8*)(dstp + s * 8) =
                    *(const short8*)&xs[r * 128 + ((s ^ (r & 7)) * 8)];
            }
        }
    }
}

// ---- CSR aggregation (R6 version, known-good): fp16 gather (16B/lane,
// 4 edges/wave-instr), fp32 accumulate, fp16 out. One node per wave.
template<bool RELU>
__global__ __launch_bounds__(256)
void k_agg(const _Float16* __restrict__ Hin, const int* __restrict__ off,
           const unsigned short* __restrict__ srcs, const float* __restrict__ bias,
           _Float16* __restrict__ Hout)
{
    const int lane = threadIdx.x & 63;
    const int es   = lane >> 4;          // 0..3  edge slot
    const int q    = lane & 15;          // col group 8q..8q+7
    const int wv   = threadIdx.x >> 6;
    const int n    = blockIdx.x * 4 + wv;
    const int j0 = __builtin_amdgcn_readfirstlane(off[n]);
    const int j1 = __builtin_amdgcn_readfirstlane(off[n + 1]);

    float acc[8] = {};
    int j = j0;

    for (; j + 16 <= j1; j += 16) {
        half8 v[4];
        #pragma unroll
        for (int k = 0; k < 4; ++k) {
            int s = srcs[j + 4 * k + es];
            v[k] = *(const half8*)(Hin + (size_t)s * D + q * 8);
        }
        #pragma unroll
        for (int k = 0; k < 4; ++k)
            #pragma unroll
            for (int c = 0; c < 8; ++c) acc[c] += (float)v[k][c];
    }
    for (; j + 4 <= j1; j += 4) {
        int s = srcs[j + es];
        half8 v = *(const half8*)(Hin + (size_t)s * D + q * 8);
        #pragma unroll
        for (int c = 0; c < 8; ++c) acc[c] += (float)v[c];
    }
    {
        int rem = j1 - j;            // 0..3
        if (rem > 0) {
            int s = srcs[j + (es < rem ? es : rem - 1)];
            half8 v = *(const half8*)(Hin + (size_t)s * D + q * 8);
            if (es < rem) {
                #pragma unroll
                for (int c = 0; c < 8; ++c) acc[c] += (float)v[c];
            }
        }
    }

    #pragma unroll
    for (int c = 0; c < 8; ++c) {
        acc[c] += __shfl_xor(acc[c], 16, 64);
        acc[c] += __shfl_xor(acc[c], 32, 64);
    }

    if (es == 0) {
        half8 o;
        #pragma unroll
        for (int c = 0; c < 8; ++c) {
            float t = acc[c] + bias[q * 8 + c];
            if (RELU) t = fmaxf(t, 0.f);
            o[c] = (_Float16)t;
        }
        *(half8*)(Hout + (size_t)n * D + q * 8) = o;
    }
}

// ---- MFMA link predictor: 256 thr / 64 edges per block, fp16 emb gather ----
__global__ __launch_bounds__(256)
void k_predm(const _Float16* __restrict__ emb, const int* __restrict__ te,
             const short* __restrict__ P1T, const float* __restrict__ pb1,
             const short* __restrict__ P2T, const float* __restrict__ pb2,
             const float* __restrict__ P3, const float* __restrict__ pb3,
             float* __restrict__ out)
{
    __shared__ __align__(16) short xs[64 * 128];
    __shared__ float red[64][8];
    const int tid = threadIdx.x;
    const int l   = tid & 63;
    const int w   = tid >> 6;
    const int g   = l >> 4;
    const int l15 = l & 15;
    const int row0 = blockIdx.x * 64;

    // stage z0 = emb[s] * emb[d] -> bf16 LDS (swizzled)
    {
        int r = tid >> 2;
        int e = row0 + r; if (e >= N_QE) e = N_QE - 1;
        const int2 ee = *(const int2*)(te + 2 * e);
        const _Float16* sp = emb + (size_t)ee.x * D;
        const _Float16* dp = emb + (size_t)ee.y * D;
        #pragma unroll
        for (int it = 0; it < 4; ++it) {
            int s = (tid & 3) + it * 4;
            half8 a = *(const half8*)(sp + s * 8);
            half8 b = *(const half8*)(dp + s * 8);
            short8 h;
            #pragma unroll
            for (int c = 0; c < 8; ++c) h[c] = f2bf((float)a[c] * (float)b[c]);
            *(short8*)&xs[r * 128 + ((s ^ (r & 7)) * 8)] = h;
        }
    }
    __syncthreads();

    f32x4 acc[4][2];

    // ---------------- layer 1 ----------------
    {
        short8 wf[2][4];
        #pragma unroll
        for (int tt = 0; tt < 2; ++tt) {
            int c = w * 32 + tt * 16 + l15;
            #pragma unroll
            for (int s = 0; s < 4; ++s)
                wf[tt][s] = *(const short8*)(P1T + (size_t)c * 128 + s * 32 + g * 8);
        }
        #pragma unroll
        for (int rt = 0; rt < 4; ++rt)
            #pragma unroll
            for (int tt = 0; tt < 2; ++tt)
                acc[rt][tt] = (f32x4){0.f, 0.f, 0.f, 0.f};

        #pragma unroll
        for (int rt = 0; rt < 4; ++rt) {
            const int r = rt * 16 + l15;
            short8 a[4];
            #pragma unroll
            for (int s = 0; s < 4; ++s) {
                int slot = (4 * s + g) ^ (r & 7);
                a[s] = *(const short8*)&xs[r * 128 + slot * 8];
            }
            #pragma unroll
            for (int tt = 0; tt < 2; ++tt)
                #pragma unroll
                for (int s = 0; s < 4; ++s)
                    acc[rt][tt] = __builtin_amdgcn_mfma_f32_16x16x32_bf16(
                        a[s], wf[tt][s], acc[rt][tt], 0, 0, 0);
        }

        float bv[2];
        #pragma unroll
        for (int tt = 0; tt < 2; ++tt) bv[tt] = pb1[w * 32 + tt * 16 + l15];

        __syncthreads();   // reads done before overwrite

        #pragma unroll
        for (int rt = 0; rt < 4; ++rt)
            #pragma unroll
            for (int tt = 0; tt < 2; ++tt) {
                int c = w * 32 + tt * 16 + l15;
                #pragma unroll
                for (int i = 0; i < 4; ++i) {
                    float v = fmaxf(acc[rt][tt][i] + bv[tt], 0.f);
                    int row = rt * 16 + g * 4 + i;
                    int slot = (c >> 3) ^ (row & 7);
                    xs[row * 128 + slot * 8 + (c & 7)] = f2bf(v);
                }
            }
        __syncthreads();
    }

    // ---------------- layer 2 (acc kept for epilogue) ----------------
    {
        short8 wf[2][4];
        #pragma unroll
        for (int tt = 0; tt < 2; ++tt) {
            int c = w * 32 + tt * 16 + l15;
            #pragma unroll
            for (int s = 0; s < 4; ++s)
                wf[tt][s] = *(const short8*)(P2T + (size_t)c * 128 + s * 32 + g * 8);
        }
        #pragma unroll
        for (int rt = 0; rt < 4; ++rt)
            #pragma unroll
            for (int tt = 0; tt < 2; ++tt)
                acc[rt][tt] = (f32x4){0.f, 0.f, 0.f, 0.f};

        #pragma unroll
        for (int rt = 0; rt < 4; ++rt) {
            const int r = rt * 16 + l15;
            short8 a[4];
            #pragma unroll
            for (int s = 0; s < 4; ++s) {
                int slot = (4 * s + g) ^ (r & 7);
                a[s] = *(const short8*)&xs[r * 128 + slot * 8];
            }
            #pragma unroll
            for (int tt = 0; tt < 2; ++tt)
                #pragma unroll
                for (int s = 0; s < 4; ++s)
                    acc[rt][tt] = __builtin_amdgcn_mfma_f32_16x16x32_bf16(
                        a[s], wf[tt][s], acc[rt][tt], 0, 0, 0);
        }
    }

    // bias + relu on layer-2 acc, then P3 partials + reduce
    {
        float bv[2];
        float2 p3v[2];
        #pragma unroll
        for (int tt = 0; tt < 2; ++tt) {
            int c = w * 32 + tt * 16 + l15;
            bv[tt] = pb2[c];
            p3v[tt] = *(const float2*)(P3 + c * 2);
        }
        #pragma unroll
        for (int rt = 0; rt < 4; ++rt)
            #pragma unroll
            for (int i = 0; i < 4; ++i) {
                float z0 = fmaxf(acc[rt][0][i] + bv[0], 0.f);
                float z1 = fmaxf(acc[rt][1][i] + bv[1], 0.f);
                float p0 = z0 * p3v[0].x + z1 * p3v[1].x;
                float p1 = z0 * p3v[0].y + z1 * p3v[1].y;
                #pragma unroll
                for (int o = 1; o < 16; o <<= 1) {
                    p0 += __shfl_xor(p0, o, 64);
                    p1 += __shfl_xor(p1, o, 64);
                }
                if (l15 == 0) {
                    int row = rt * 16 + g * 4 + i;
                    red[row][w * 2]     = p0;
                    red[row][w * 2 + 1] = p1;
                }
            }
    }
    __syncthreads();

    if (tid < 64) {
        int gr = row0 + tid;
        if (gr < N_QE) {
            float p0 = red[tid][0] + red[tid][2] + red[tid][4] + red[tid][6] + pb3[0];
            float p1 = red[tid][1] + red[tid][3] + red[tid][5] + red[tid][7] + pb3[1];
            float nrm = fmaxf(sqrtf(p0 * p0 + p1 * p1), 1e-12f);
            p0 /= nrm; p1 /= nrm;
            float m = fmaxf(p0, p1);
            float lse = m + logf(expf(p0 - m) + expf(p1 - m));
            out[gr * 2]     = p0 - lse;
            out[gr * 2 + 1] = p1 - lse;
        }
    }
}

extern "C" void kernel_launch(void* const* d_in, const int* in_sizes, int n_in,
                              void* d_out, int out_size, void* d_ws, size_t ws_size,
                              hipStream_t stream)
{
    (void)in_sizes; (void)n_in; (void)out_size; (void)ws_size;
    const float* x   = (const float*)d_in[0];
    const int*   adj = (const int*)d_in[1];
    const int*   te  = (const int*)d_in[2];
    const float* W1  = (const float*)d_in[3];
    const float* b1  = (const float*)d_in[4];
    const float* W2  = (const float*)d_in[5];
    const float* b2  = (const float*)d_in[6];
    const float* W3  = (const float*)d_in[7];
    const float* b3  = (const float*)d_in[8];
    const float* P1  = (const float*)d_in[9];
    const float* pb1 = (const float*)d_in[10];
    const float* P2  = (const float*)d_in[11];
    const float* pb2 = (const float*)d_in[12];
    const float* P3  = (const float*)d_in[13];
    const float* pb3 = (const float*)d_in[14];
    float* out = (float*)d_out;

    char* ws = (char*)d_ws;
    int* bcnt = (int*)(ws + O_BCNT);
    int* off  = (int*)(ws + O_OFF);
    int* bcur = (int*)(ws + O_BC);
    int* bbase= (int*)(ws + O_BB);
    unsigned short* srcs = (unsigned short*)(ws + O_SRC);
    unsigned* tmp = (unsigned*)(ws + O_TMP);
    _Float16* G = (_Float16*)(ws + O_G);    // fp16 agg output / emb
    _Float16* H = (_Float16*)(ws + O_H);    // fp16 gemm output (gather source)
    short*    T = (short*)(ws + O_T);       // bf16 transposed weights (5x 128x128)

    const int* esrc = adj;
    const int* edst = adj + N_EDGES;
    const int NCHUNK = (N_EDGES + PCHUNK - 1) / PCHUNK;   // 98

    // transposed bf16 weights (all 5 dense layers)
    k_t16all<<<320, 256, 0, stream>>>(W1, W2, W3, P1, P2, T);

    // CSR build: bucket count -> bucket scan -> partition -> fine(off+scatter)
    hipMemsetAsync(bcnt, 0, NB * sizeof(int), stream);
    k_bcount<<<NCHUNK, 256, 0, stream>>>(edst, bcnt);
    k_bscan<<<1, 512, 0, stream>>>(bcnt, bbase, bcur, off);
    k_part<<<NCHUNK, 256, 0, stream>>>(esrc, edst, bcur, tmp);
    k_fine2<<<NB, 256, 0, stream>>>(tmp, bbase, srcs, off);

    const int gN = (N_NODES + 63) / 64;   // 782

    // GCN trunk: bf16-MFMA gemm (fp16 out) -> agg (fp16 gather, fp16 out)
    k_mm<float><<<gN, 256, 0, stream>>>(x, T, H, N_NODES);
    k_agg<true><<<N_NODES / 4, 256, 0, stream>>>(H, off, srcs, b1, G);
    k_mm<_Float16><<<gN, 256, 0, stream>>>(G, T + 16384, H, N_NODES);
    k_agg<true><<<N_NODES / 4, 256, 0, stream>>>(H, off, srcs, b2, G);
    k_mm<_Float16><<<gN, 256, 0, stream>>>(G, T + 2 * 16384, H, N_NODES);
    k_agg<false><<<N_NODES / 4, 256, 0, stream>>>(H, off, srcs, b3, G); // G = emb

    // bf16-MFMA link predictor (fp16 emb gather)
    const int gQ = (N_QE + 63) / 64;      // 1563
    k_predm<<<gQ, 256, 0, stream>>>(G, te, T + 3 * 16384, pb1,
                                    T + 4 * 16384, pb2, P3, pb3, out);
}